// Round 3
// baseline (7279.878 us; speedup 1.0000x reference)
//
#include <hip/hip_runtime.h>
#include <math.h>

#define BATCH  256
#define CODE   64
#define HID    256
#define TSTEPS 640     // 512 encoder + 128 decoder steps
#define NB     16
#define GWG    16
#define NGRP   16

// ---- workspace layout (float offsets)
#define OFF_A0   0          // [64rt][10f][2pl][64lane][16B bf16]  = 327680 floats
#define OFF_A1   327680     // [64rt][16f][2pl][64lane][16B bf16]  = 524288 floats
#define OFF_BP0  851968     // [1024] permuted fused bias layer0
#define OFF_BP1  852992     // [1024]
#define OFF_H0EX 854016     // [2buf][16grp][16batch][256unit] bf16 = 65536 floats
#define OFF_H1EX 919552     // same
#define OFF_CNT  985088     // 16 groups * 32 flag words
#define WS_FLOATS (OFF_CNT + 512)

typedef __attribute__((ext_vector_type(8))) short  short8;
typedef __attribute__((ext_vector_type(4))) float  f32x4;
typedef __attribute__((ext_vector_type(8))) __bf16 bf16x8;
typedef unsigned long long u64;

__device__ __forceinline__ f32x4 mfma16(short8 a, short8 b, f32x4 c) {
  return __builtin_amdgcn_mfma_f32_16x16x32_bf16(
      __builtin_bit_cast(bf16x8, a), __builtin_bit_cast(bf16x8, b), c, 0, 0, 0);
}
__device__ __forceinline__ unsigned short f2bf(float f) {
  union { float f; unsigned u; } v{f};
  unsigned r = v.u + 0x7fffu + ((v.u >> 16) & 1u);   // RNE
  return (unsigned short)(r >> 16);
}
__device__ __forceinline__ float bf2f(unsigned short b) {
  union { unsigned u; float f; } v{(unsigned)b << 16};
  return v.f;
}
__device__ __forceinline__ u64 ld8(const u64* p) {
  return __hip_atomic_load(p, __ATOMIC_RELAXED, __HIP_MEMORY_SCOPE_AGENT);
}
__device__ __forceinline__ void st8(u64* p, u64 v) {
  __hip_atomic_store(p, v, __ATOMIC_RELAXED, __HIP_MEMORY_SCOPE_AGENT);
}
__device__ __forceinline__ float sigm(float v) { return 1.0f / (1.0f + expf(-v)); }

// ---- one-time weight swizzle into MFMA fragment order, hi/lo bf16 split.
__global__ void setup_kernel(const float* __restrict__ Wih0, const float* __restrict__ Whh0,
                             const float* __restrict__ bih0, const float* __restrict__ bhh0,
                             const float* __restrict__ Wih1, const float* __restrict__ Whh1,
                             const float* __restrict__ bih1, const float* __restrict__ bhh1,
                             float* __restrict__ ws) {
  int i = blockIdx.x * 256 + threadIdx.x;
  unsigned short* u = (unsigned short*)ws;
  if (i < 327680) {        // layer0: K = 320 (64 x | 256 h0)
    int rt = i / 5120, r = i % 5120;
    int f = r >> 9, l = (r >> 3) & 63, j = r & 7;
    int p = rt * 16 + (l & 15);
    int orig = (p & 3) * 256 + (p >> 2);
    int k = f * 32 + ((l >> 4) << 3) + j;
    float w = (k < 64) ? Wih0[orig * 64 + k] : Whh0[orig * 256 + k - 64];
    unsigned short hi = f2bf(w);
    unsigned short lo = f2bf(w - bf2f(hi));
    int base = OFF_A0 * 2 + (((rt * 10 + f) * 2) * 64 + l) * 8 + j;
    u[base] = hi; u[base + 512] = lo;
    return;
  }
  i -= 327680;
  if (i < 524288) {        // layer1: K = 512 (256 h0 | 256 h1)
    int rt = i >> 13, r = i & 8191;
    int f = r >> 9, l = (r >> 3) & 63, j = r & 7;
    int p = rt * 16 + (l & 15);
    int orig = (p & 3) * 256 + (p >> 2);
    int k = f * 32 + ((l >> 4) << 3) + j;
    float w = (k < 256) ? Wih1[orig * 256 + k] : Whh1[orig * 256 + k - 256];
    unsigned short hi = f2bf(w);
    unsigned short lo = f2bf(w - bf2f(hi));
    int base = OFF_A1 * 2 + (((rt * 16 + f) * 2) * 64 + l) * 8 + j;
    u[base] = hi; u[base + 512] = lo;
    return;
  }
  i -= 524288;
  if (i < 2048) {
    int layer = i >> 10, p = i & 1023;
    int orig = (p & 3) * 256 + (p >> 2);
    ws[OFF_BP0 + i] = layer ? (bih1[orig] + bhh1[orig]) : (bih0[orig] + bhh0[orig]);
  }
}

// ---- persistent MFMA LSTM with flag/token sync.
// 256 WGs x 512 thr; 16 groups x 16 WGs. waves 0-3: layer0 (step T);
// waves 4-7: layer1 (step T-1). End-phase roles: w0/w1 x-prefetch, w2 export
// h0 + flag, w6 export h1 + flag, w3 FC projection, w7 global poll -> token.
__global__ __launch_bounds__(512, 2) void lstm_mfma(
    const float* __restrict__ x, const float* __restrict__ targets,
    const float* __restrict__ fcW, const float* __restrict__ fcb,
    float* __restrict__ ws, float* __restrict__ out) {
  __shared__ __align__(16) short Bx[2][2][64][8];     // x frags, dbuf
  __shared__ __align__(16) short Bh0[8][64][8];       // h0 frags
  __shared__ __align__(16) short Bh1[2][8][64][8];    // h1 frags, dbuf (FC reads)
  __shared__ float hstage[2][16][20];                 // [layer][batch][unit] pad 20
  __shared__ float fcw_s[64 * 257];
  __shared__ int lds_token;

  const int t = threadIdx.x;
  const int blk = blockIdx.x;
  const int xcd = blk & 7, slot = blk >> 3;
  const int grp = xcd * 2 + (slot >> 4);   // 0..15
  const int wg  = slot & 15;               // 0..15

  const int w = t >> 6, l = t & 63, wl = w & 3;
  const bool isL0 = (w < 4);
  const int rt = wg * 4 + wl;

  unsigned short* h0ex = (unsigned short*)(ws + OFF_H0EX);
  unsigned short* h1ex = (unsigned short*)(ws + OFF_H1EX);
  unsigned* flags = (unsigned*)(ws + OFF_CNT) + grp * 32;

  if (t == 0) lds_token = 0;
  for (int idx = t; idx < 64 * 256; idx += 512)
    fcw_s[(idx >> 8) * 257 + (idx & 255)] = fcW[idx];

  // ---- register-resident A fragments
  short8 Ah[16], Al[16];
  if (isL0) {
    const float* Ab = ws + OFF_A0 + rt * 5120;
#pragma unroll
    for (int f = 0; f < 10; ++f) {
      Ah[f] = *(const short8*)(Ab + ((f * 2 + 0) * 64 + l) * 4);
      Al[f] = *(const short8*)(Ab + ((f * 2 + 1) * 64 + l) * 4);
    }
  } else {
    const float* Ab = ws + OFF_A1 + rt * 8192;
#pragma unroll
    for (int f = 0; f < 16; ++f) {
      Ah[f] = *(const short8*)(Ab + ((f * 2 + 0) * 64 + l) * 4);
      Al[f] = *(const short8*)(Ab + ((f * 2 + 1) * 64 + l) * 4);
    }
  }
  const f32x4 bias = *(const f32x4*)(ws + (isL0 ? OFF_BP0 : OFF_BP1) + rt * 16 + ((l >> 4) << 2));
  const float fcb_r = fcb[4 * wg + (l & 3)];
  float cst = 0.0f;

  const int col = l & 15;
  const int k0 = (w << 5) + ((l >> 4) << 3);

  float4 xr0, xr1;
  auto load_x = [&](int s) {     // issue global loads for step s into regs
    if (w < 2 && s < TSTEPS) {
      const float* src;
      if (s <= 512) {
        int ss = (s < 512) ? s : 511;
        src = x + ((size_t)(grp * 16 + col) * 512 + ss) * 64 + k0;
      } else {
        src = targets + ((size_t)(grp * 16 + col) * 128 + (s - 513)) * 64 + k0;
      }
      xr0 = *(const float4*)src;
      xr1 = *(const float4*)(src + 4);
    }
  };
  auto put_x = [&](int p) {      // regs -> Bx[p][w]
    if (w < 2) {
      short8 v;
      v[0] = (short)f2bf(xr0.x); v[1] = (short)f2bf(xr0.y);
      v[2] = (short)f2bf(xr0.z); v[3] = (short)f2bf(xr0.w);
      v[4] = (short)f2bf(xr1.x); v[5] = (short)f2bf(xr1.y);
      v[6] = (short)f2bf(xr1.z); v[7] = (short)f2bf(xr1.w);
      *(short8*)Bx[p][w][l] = v;
    }
  };

  load_x(0);

  for (int T = 0; T <= TSTEPS + 1; ++T) {
    const int rp = (T + 1) & 1, wp = T & 1;

    // ---- wait for group tick T (token set by wave 7 at end of T-1)
    if (T >= 1) {
      while (__hip_atomic_load(&lds_token, __ATOMIC_ACQUIRE,
                               __HIP_MEMORY_SCOPE_WORKGROUP) < T) { }
    }

    // ---- stage h0(T-1), h1(T-2) frags (L3 -> LDS, lane-identity layout)
    {
      const u64* p0 = (const u64*)(h0ex + ((((rp * 16) + grp) * 16 + col) << 8) + k0);
      const u64* p1 = (const u64*)(h1ex + ((((rp * 16) + grp) * 16 + col) << 8) + k0);
      union { u64 q[2]; short8 v; } U0, U1;
      U0.q[0] = ld8(p0); U0.q[1] = ld8(p0 + 1);
      U1.q[0] = ld8(p1); U1.q[1] = ld8(p1 + 1);
      *(short8*)Bh0[w][l] = U0.v;
      *(short8*)Bh1[wp][w][l] = U1.v;
    }
    if (T < TSTEPS) put_x(wp);
    __syncthreads();

    // ---- gate MFMA (hi/lo planes, 2 independent chains each) + pointwise
    {
      const bool act = isL0 ? (T < TSTEPS) : (T >= 1 && T <= TSTEPS);
      if (act) {
        f32x4 aH0 = {0.f,0.f,0.f,0.f}, aH1 = {0.f,0.f,0.f,0.f};
        f32x4 aL0 = {0.f,0.f,0.f,0.f}, aL1 = {0.f,0.f,0.f,0.f};
        if (isL0) {
          {
            short8 b0 = *(const short8*)Bx[wp][0][l];
            aH0 = mfma16(Ah[0], b0, aH0); aL0 = mfma16(Al[0], b0, aL0);
            short8 b1 = *(const short8*)Bx[wp][1][l];
            aH1 = mfma16(Ah[1], b1, aH1); aL1 = mfma16(Al[1], b1, aL1);
          }
#pragma unroll
          for (int f = 2; f < 10; ++f) {
            short8 b = *(const short8*)Bh0[f - 2][l];
            if (f & 1) { aH1 = mfma16(Ah[f], b, aH1); aL1 = mfma16(Al[f], b, aL1); }
            else       { aH0 = mfma16(Ah[f], b, aH0); aL0 = mfma16(Al[f], b, aL0); }
          }
        } else {
#pragma unroll
          for (int f = 0; f < 8; ++f) {
            short8 b = *(const short8*)Bh0[f][l];
            if (f & 1) { aH1 = mfma16(Ah[f], b, aH1); aL1 = mfma16(Al[f], b, aL1); }
            else       { aH0 = mfma16(Ah[f], b, aH0); aL0 = mfma16(Al[f], b, aL0); }
          }
#pragma unroll
          for (int f = 8; f < 16; ++f) {
            short8 b = *(const short8*)Bh1[wp][f - 8][l];
            if (f & 1) { aH1 = mfma16(Ah[f], b, aH1); aL1 = mfma16(Al[f], b, aL1); }
            else       { aH0 = mfma16(Ah[f], b, aH0); aL0 = mfma16(Al[f], b, aL0); }
          }
        }
        f32x4 s = aH0 + aH1 + aL0 + aL1 + bias;
        cst = sigm(s.y) * cst + sigm(s.x) * tanhf(s.z);
        float hh = sigm(s.w) * tanhf(cst);
        hstage[isL0 ? 0 : 1][l & 15][4 * wl + (l >> 4)] = hh;
      }
    }
    __syncthreads();

    // ---- end-phase (per-wave roles, no further intra-WG barrier this tick)
    if (w == 2 || w == 6) {           // export + flag
      const int e = (w == 2) ? 0 : 1;
      const bool valid = e ? (T >= 1 && T <= TSTEPS) : (T < TSTEPS);
      if (valid) {
        int b = l >> 2, q = l & 3;
        float4 hv = *(const float4*)&hstage[e][b][q * 4];
        u64 qv; unsigned short* qq = (unsigned short*)&qv;
        qq[0] = f2bf(hv.x); qq[1] = f2bf(hv.y);
        qq[2] = f2bf(hv.z); qq[3] = f2bf(hv.w);
        unsigned short* dst = (e ? h1ex : h0ex) +
            ((((wp * 16) + grp) * 16 + b) << 8) + (wg << 4) + (q << 2);
        st8((u64*)dst, qv);
      }
      if (T <= TSTEPS && l == 0) {
        __hip_atomic_store(&flags[2 * wg + ((w == 2) ? 0 : 1)], (unsigned)(T + 1),
                           __ATOMIC_RELEASE, __HIP_MEMORY_SCOPE_AGENT);
      }
    }
    if (w < 2 && (T + 1) < TSTEPS) load_x(T + 1);   // prefetch next x into regs
    if (w == 3 && T >= 514) {         // FC projection, hidden under poll window
      int d = T - 514;
      int code = 4 * wg + (l & 3), b = l >> 2;
      float acc = fcb_r;
#pragma unroll 4
      for (int k8 = 0; k8 < 32; ++k8) {
        short8 hv = *(const short8*)Bh1[wp][k8 >> 2][(k8 & 3) * 16 + b];
#pragma unroll
        for (int j = 0; j < 8; ++j)
          acc = fmaf(fcw_s[code * 257 + k8 * 8 + j], bf2f((unsigned short)hv[j]), acc);
      }
      __builtin_nontemporal_store(acc, &out[(size_t)(grp * 16 + b) * 8192 + d * 64 + code]);
    }
    if (w == 7 && T <= TSTEPS) {      // poll all 32 flags of the group
      const unsigned tgt = (unsigned)(T + 1);
      bool ok;
      do {
        unsigned v = __hip_atomic_load(&flags[l & 31], __ATOMIC_RELAXED,
                                       __HIP_MEMORY_SCOPE_AGENT);
        ok = __all((l < 32) ? (v >= tgt) : 1);
      } while (!ok);
      __builtin_amdgcn_fence(__ATOMIC_ACQUIRE, "agent");
      if (l == 0)
        __hip_atomic_store(&lds_token, T + 1, __ATOMIC_RELEASE,
                           __HIP_MEMORY_SCOPE_WORKGROUP);
    }
  }
}

extern "C" void kernel_launch(void* const* d_in, const int* in_sizes, int n_in,
                              void* d_out, int out_size, void* d_ws, size_t ws_size,
                              hipStream_t stream) {
  const float* x       = (const float*)d_in[0];
  const float* targets = (const float*)d_in[1];
  const float* Wih0    = (const float*)d_in[2];
  const float* Whh0    = (const float*)d_in[3];
  const float* bih0    = (const float*)d_in[4];
  const float* bhh0    = (const float*)d_in[5];
  const float* Wih1    = (const float*)d_in[6];
  const float* Whh1    = (const float*)d_in[7];
  const float* bih1    = (const float*)d_in[8];
  const float* bhh1    = (const float*)d_in[9];
  const float* fcW     = (const float*)d_in[10];
  const float* fcb     = (const float*)d_in[11];
  float* ws = (float*)d_ws;
  float* o  = (float*)d_out;

  // zero h-exchange buffers + flags every call (deterministic)
  hipMemsetAsync((char*)d_ws + (size_t)OFF_H0EX * 4, 0,
                 (size_t)(WS_FLOATS - OFF_H0EX) * 4, stream);
  setup_kernel<<<3336, 256, 0, stream>>>(Wih0, Whh0, bih0, bhh0,
                                         Wih1, Whh1, bih1, bhh1, ws);
  lstm_mfma<<<256, 512, 0, stream>>>(x, targets, fcW, fcb, ws, o);
}

// Round 4
// 3589.875 us; speedup vs baseline: 2.0279x; 2.0279x over previous
//
#include <hip/hip_runtime.h>
#include <math.h>

#define BATCH  256
#define CODE   64
#define HID    256
#define TSTEPS 640     // 512 encoder + 128 decoder steps
#define NB     16
#define GWG    16
#define NGRP   16

// ---- workspace layout (float offsets)
#define OFF_A0   0          // [64rt][10f][2pl][64lane][16B bf16]  = 327680 floats
#define OFF_A1   327680     // [64rt][16f][2pl][64lane][16B bf16]  = 524288 floats
#define OFF_BP0  851968     // [1024] permuted fused bias layer0
#define OFF_BP1  852992     // [1024]
#define OFF_H0EX 854016     // [2buf][16grp][16batch][256unit] bf16 = 65536 floats
#define OFF_H1EX 919552     // same
#define OFF_CNT  985088     // 16 groups * 32 flag words (1 used per WG)
#define WS_FLOATS (OFF_CNT + 512)

typedef __attribute__((ext_vector_type(8))) short  short8;
typedef __attribute__((ext_vector_type(4))) float  f32x4;
typedef __attribute__((ext_vector_type(8))) __bf16 bf16x8;
typedef unsigned long long u64;

__device__ __forceinline__ f32x4 mfma16(short8 a, short8 b, f32x4 c) {
  return __builtin_amdgcn_mfma_f32_16x16x32_bf16(
      __builtin_bit_cast(bf16x8, a), __builtin_bit_cast(bf16x8, b), c, 0, 0, 0);
}
__device__ __forceinline__ unsigned short f2bf(float f) {
  union { float f; unsigned u; } v{f};
  unsigned r = v.u + 0x7fffu + ((v.u >> 16) & 1u);   // RNE
  return (unsigned short)(r >> 16);
}
__device__ __forceinline__ float bf2f(unsigned short b) {
  union { unsigned u; float f; } v{(unsigned)b << 16};
  return v.f;
}
__device__ __forceinline__ u64 ld8(const u64* p) {
  return __hip_atomic_load(p, __ATOMIC_RELAXED, __HIP_MEMORY_SCOPE_AGENT);
}
__device__ __forceinline__ void st8(u64* p, u64 v) {
  __hip_atomic_store(p, v, __ATOMIC_RELAXED, __HIP_MEMORY_SCOPE_AGENT);
}
#define LOG2E 1.4426950408889634f
__device__ __forceinline__ float sigm(float x) {
  return __builtin_amdgcn_rcpf(1.0f + __builtin_amdgcn_exp2f(-x * LOG2E));
}
__device__ __forceinline__ float tanh_f(float x) {
  // 1 - 2/(e^{2x}+1); exp2 overflow -> inf -> rcp -> 0 -> 1 (correct saturation)
  return 1.0f - 2.0f * __builtin_amdgcn_rcpf(1.0f + __builtin_amdgcn_exp2f(x * (2.0f * LOG2E)));
}

// ---- one-time weight swizzle into MFMA fragment order, hi/lo bf16 split.
__global__ void setup_kernel(const float* __restrict__ Wih0, const float* __restrict__ Whh0,
                             const float* __restrict__ bih0, const float* __restrict__ bhh0,
                             const float* __restrict__ Wih1, const float* __restrict__ Whh1,
                             const float* __restrict__ bih1, const float* __restrict__ bhh1,
                             float* __restrict__ ws) {
  int i = blockIdx.x * 256 + threadIdx.x;
  unsigned short* u = (unsigned short*)ws;
  if (i < 327680) {        // layer0: K = 320 (64 x | 256 h0)
    int rt = i / 5120, r = i % 5120;
    int f = r >> 9, l = (r >> 3) & 63, j = r & 7;
    int p = rt * 16 + (l & 15);
    int orig = (p & 3) * 256 + (p >> 2);
    int k = f * 32 + ((l >> 4) << 3) + j;
    float w = (k < 64) ? Wih0[orig * 64 + k] : Whh0[orig * 256 + k - 64];
    unsigned short hi = f2bf(w);
    unsigned short lo = f2bf(w - bf2f(hi));
    int base = OFF_A0 * 2 + (((rt * 10 + f) * 2) * 64 + l) * 8 + j;
    u[base] = hi; u[base + 512] = lo;
    return;
  }
  i -= 327680;
  if (i < 524288) {        // layer1: K = 512 (256 h0 | 256 h1)
    int rt = i >> 13, r = i & 8191;
    int f = r >> 9, l = (r >> 3) & 63, j = r & 7;
    int p = rt * 16 + (l & 15);
    int orig = (p & 3) * 256 + (p >> 2);
    int k = f * 32 + ((l >> 4) << 3) + j;
    float w = (k < 256) ? Wih1[orig * 256 + k] : Whh1[orig * 256 + k - 256];
    unsigned short hi = f2bf(w);
    unsigned short lo = f2bf(w - bf2f(hi));
    int base = OFF_A1 * 2 + (((rt * 16 + f) * 2) * 64 + l) * 8 + j;
    u[base] = hi; u[base + 512] = lo;
    return;
  }
  i -= 524288;
  if (i < 2048) {
    int layer = i >> 10, p = i & 1023;
    int orig = (p & 3) * 256 + (p >> 2);
    ws[OFF_BP0 + i] = layer ? (bih1[orig] + bhh1[orig]) : (bih0[orig] + bhh0[orig]);
  }
}

// ---- persistent MFMA LSTM. 256 WGs x 512 thr; 16 groups x 16 WGs.
// waves 0-3: layer0 (step T); waves 4-7: layer1 (step T-1).
// End-phase roles: w0/w1 x-prefetch(regs), w2 export h0+h1 then release flag,
// w3 FC projection, w7 poll 16 flags (relaxed + s_sleep backoff).
// All waves wait at s_barrier (quiescent) -- no LDS spinning.
__global__ __launch_bounds__(512, 2) void lstm_mfma(
    const float* __restrict__ x, const float* __restrict__ targets,
    const float* __restrict__ fcW, const float* __restrict__ fcb,
    float* __restrict__ ws, float* __restrict__ out) {
  __shared__ __align__(16) short Bx[2][2][64][8];     // x frags, dbuf
  __shared__ __align__(16) short Bh0[8][64][8];       // h0 frags
  __shared__ __align__(16) short Bh1[2][8][64][8];    // h1 frags, dbuf (FC reads)
  __shared__ float hstage[2][16][20];                 // [layer][batch][unit] pad 20
  __shared__ float fcw_s[64 * 257];

  const int t = threadIdx.x;
  const int blk = blockIdx.x;
  const int xcd = blk & 7, slot = blk >> 3;
  const int grp = xcd * 2 + (slot >> 4);   // 0..15
  const int wg  = slot & 15;               // 0..15

  const int w = t >> 6, l = t & 63, wl = w & 3;
  const bool isL0 = (w < 4);
  const int rt = wg * 4 + wl;

  unsigned short* h0ex = (unsigned short*)(ws + OFF_H0EX);
  unsigned short* h1ex = (unsigned short*)(ws + OFF_H1EX);
  unsigned* flags = (unsigned*)(ws + OFF_CNT) + grp * 32;

  for (int idx = t; idx < 64 * 256; idx += 512)
    fcw_s[(idx >> 8) * 257 + (idx & 255)] = fcW[idx];

  // ---- register-resident A fragments
  short8 Ah[16], Al[16];
  if (isL0) {
    const float* Ab = ws + OFF_A0 + rt * 5120;
#pragma unroll
    for (int f = 0; f < 10; ++f) {
      Ah[f] = *(const short8*)(Ab + ((f * 2 + 0) * 64 + l) * 4);
      Al[f] = *(const short8*)(Ab + ((f * 2 + 1) * 64 + l) * 4);
    }
  } else {
    const float* Ab = ws + OFF_A1 + rt * 8192;
#pragma unroll
    for (int f = 0; f < 16; ++f) {
      Ah[f] = *(const short8*)(Ab + ((f * 2 + 0) * 64 + l) * 4);
      Al[f] = *(const short8*)(Ab + ((f * 2 + 1) * 64 + l) * 4);
    }
  }
  const f32x4 bias = *(const f32x4*)(ws + (isL0 ? OFF_BP0 : OFF_BP1) + rt * 16 + ((l >> 4) << 2));
  const float fcb_r = fcb[4 * wg + (l & 3)];
  float cst = 0.0f;

  const int col = l & 15;
  const int k0 = (w << 5) + ((l >> 4) << 3);

  float4 xr0, xr1;
  auto load_x = [&](int s) {     // issue global loads for step s into regs
    if (w < 2 && s < TSTEPS) {
      const float* src;
      if (s <= 512) {
        int ss = (s < 512) ? s : 511;
        src = x + ((size_t)(grp * 16 + col) * 512 + ss) * 64 + k0;
      } else {
        src = targets + ((size_t)(grp * 16 + col) * 128 + (s - 513)) * 64 + k0;
      }
      xr0 = *(const float4*)src;
      xr1 = *(const float4*)(src + 4);
    }
  };
  auto put_x = [&](int p) {      // regs -> Bx[p][w]
    if (w < 2) {
      short8 v;
      v[0] = (short)f2bf(xr0.x); v[1] = (short)f2bf(xr0.y);
      v[2] = (short)f2bf(xr0.z); v[3] = (short)f2bf(xr0.w);
      v[4] = (short)f2bf(xr1.x); v[5] = (short)f2bf(xr1.y);
      v[6] = (short)f2bf(xr1.z); v[7] = (short)f2bf(xr1.w);
      *(short8*)Bx[p][w][l] = v;
    }
  };

  load_x(0);

  for (int T = 0; T <= TSTEPS + 1; ++T) {
    const int rp = (T + 1) & 1, wp = T & 1;

    // ---- stage h0(T-1), h1(T-2) frags (L3 -> LDS, lane-identity layout)
    {
      const u64* p0 = (const u64*)(h0ex + ((((rp * 16) + grp) * 16 + col) << 8) + k0);
      const u64* p1 = (const u64*)(h1ex + ((((rp * 16) + grp) * 16 + col) << 8) + k0);
      union { u64 q[2]; short8 v; } U0, U1;
      U0.q[0] = ld8(p0); U0.q[1] = ld8(p0 + 1);
      U1.q[0] = ld8(p1); U1.q[1] = ld8(p1 + 1);
      *(short8*)Bh0[w][l] = U0.v;
      *(short8*)Bh1[wp][w][l] = U1.v;
    }
    if (T < TSTEPS) put_x(wp);
    __syncthreads();                                   // bar1

    // ---- gate MFMA (hi/lo planes, 4 independent chains) + pointwise
    {
      const bool act = isL0 ? (T < TSTEPS) : (T >= 1 && T <= TSTEPS);
      if (act) {
        f32x4 aH0 = {0.f,0.f,0.f,0.f}, aH1 = {0.f,0.f,0.f,0.f};
        f32x4 aL0 = {0.f,0.f,0.f,0.f}, aL1 = {0.f,0.f,0.f,0.f};
        if (isL0) {
          {
            short8 b0 = *(const short8*)Bx[wp][0][l];
            aH0 = mfma16(Ah[0], b0, aH0); aL0 = mfma16(Al[0], b0, aL0);
            short8 b1 = *(const short8*)Bx[wp][1][l];
            aH1 = mfma16(Ah[1], b1, aH1); aL1 = mfma16(Al[1], b1, aL1);
          }
#pragma unroll
          for (int f = 2; f < 10; ++f) {
            short8 b = *(const short8*)Bh0[f - 2][l];
            if (f & 1) { aH1 = mfma16(Ah[f], b, aH1); aL1 = mfma16(Al[f], b, aL1); }
            else       { aH0 = mfma16(Ah[f], b, aH0); aL0 = mfma16(Al[f], b, aL0); }
          }
        } else {
#pragma unroll
          for (int f = 0; f < 8; ++f) {
            short8 b = *(const short8*)Bh0[f][l];
            if (f & 1) { aH1 = mfma16(Ah[f], b, aH1); aL1 = mfma16(Al[f], b, aL1); }
            else       { aH0 = mfma16(Ah[f], b, aH0); aL0 = mfma16(Al[f], b, aL0); }
          }
#pragma unroll
          for (int f = 8; f < 16; ++f) {
            short8 b = *(const short8*)Bh1[wp][f - 8][l];
            if (f & 1) { aH1 = mfma16(Ah[f], b, aH1); aL1 = mfma16(Al[f], b, aL1); }
            else       { aH0 = mfma16(Ah[f], b, aH0); aL0 = mfma16(Al[f], b, aL0); }
          }
        }
        f32x4 s = aH0 + aH1 + aL0 + aL1 + bias;
        cst = sigm(s.y) * cst + sigm(s.x) * tanh_f(s.z);
        float hh = sigm(s.w) * tanh_f(cst);
        hstage[isL0 ? 0 : 1][l & 15][4 * wl + (l >> 4)] = hh;
      }
    }
    __syncthreads();                                   // bar2

    // ---- end-phase (per-wave roles), then bar3 = the tick wait
    if (w == 2) {                     // export h0(T) + h1(T-1), then flag
      int b = l >> 2, q = l & 3;
      if (T < TSTEPS) {
        float4 hv = *(const float4*)&hstage[0][b][q * 4];
        u64 qv; unsigned short* qq = (unsigned short*)&qv;
        qq[0] = f2bf(hv.x); qq[1] = f2bf(hv.y);
        qq[2] = f2bf(hv.z); qq[3] = f2bf(hv.w);
        st8((u64*)(h0ex + ((((wp * 16) + grp) * 16 + b) << 8) + (wg << 4) + (q << 2)), qv);
      }
      if (T >= 1 && T <= TSTEPS) {
        float4 hv = *(const float4*)&hstage[1][b][q * 4];
        u64 qv; unsigned short* qq = (unsigned short*)&qv;
        qq[0] = f2bf(hv.x); qq[1] = f2bf(hv.y);
        qq[2] = f2bf(hv.z); qq[3] = f2bf(hv.w);
        st8((u64*)(h1ex + ((((wp * 16) + grp) * 16 + b) << 8) + (wg << 4) + (q << 2)), qv);
      }
      if (T <= TSTEPS && l == 0)
        __hip_atomic_store(&flags[wg], (unsigned)(T + 1),
                           __ATOMIC_RELEASE, __HIP_MEMORY_SCOPE_AGENT);
    }
    if (w < 2 && (T + 1) < TSTEPS) load_x(T + 1);   // prefetch next x into regs
    if (w == 3 && T >= 514) {         // FC projection (reads Bh1[wp] = h1(T-2))
      int d = T - 514;
      int code = 4 * wg + (l & 3), b = l >> 2;
      float acc = fcb_r;
#pragma unroll 4
      for (int k8 = 0; k8 < 32; ++k8) {
        short8 hv = *(const short8*)Bh1[wp][k8 >> 2][(k8 & 3) * 16 + b];
#pragma unroll
        for (int j = 0; j < 8; ++j)
          acc = fmaf(fcw_s[code * 257 + k8 * 8 + j], bf2f((unsigned short)hv[j]), acc);
      }
      __builtin_nontemporal_store(acc, &out[(size_t)(grp * 16 + b) * 8192 + d * 64 + code]);
    }
    if (w == 7 && T <= TSTEPS) {      // poll the group's 16 WG flags
      const unsigned tgt = (unsigned)(T + 1);
      bool ok;
      do {
        unsigned v = (l < 16) ? __hip_atomic_load(&flags[l], __ATOMIC_RELAXED,
                                                  __HIP_MEMORY_SCOPE_AGENT)
                              : tgt;
        ok = __all(v >= tgt);
        if (!ok) __builtin_amdgcn_s_sleep(1);
      } while (!ok);
    }
    __syncthreads();                                   // bar3 (tick boundary)
  }
}

extern "C" void kernel_launch(void* const* d_in, const int* in_sizes, int n_in,
                              void* d_out, int out_size, void* d_ws, size_t ws_size,
                              hipStream_t stream) {
  const float* x       = (const float*)d_in[0];
  const float* targets = (const float*)d_in[1];
  const float* Wih0    = (const float*)d_in[2];
  const float* Whh0    = (const float*)d_in[3];
  const float* bih0    = (const float*)d_in[4];
  const float* bhh0    = (const float*)d_in[5];
  const float* Wih1    = (const float*)d_in[6];
  const float* Whh1    = (const float*)d_in[7];
  const float* bih1    = (const float*)d_in[8];
  const float* bhh1    = (const float*)d_in[9];
  const float* fcW     = (const float*)d_in[10];
  const float* fcb     = (const float*)d_in[11];
  float* ws = (float*)d_ws;
  float* o  = (float*)d_out;

  // zero h-exchange buffers + flags every call (deterministic)
  hipMemsetAsync((char*)d_ws + (size_t)OFF_H0EX * 4, 0,
                 (size_t)(WS_FLOATS - OFF_H0EX) * 4, stream);
  setup_kernel<<<3336, 256, 0, stream>>>(Wih0, Whh0, bih0, bhh0,
                                         Wih1, Whh1, bih1, bhh1, ws);
  lstm_mfma<<<256, 512, 0, stream>>>(x, targets, fcW, fcb, ws, o);
}

// Round 7
// 3173.092 us; speedup vs baseline: 2.2943x; 1.1313x over previous
//
#include <hip/hip_runtime.h>
#include <math.h>

#define BATCH  256
#define CODE   64
#define HID    256
#define TSTEPS 640     // 512 encoder + 128 decoder steps
#define NB     16
#define GWG    16
#define NGRP   16

// ---- workspace layout (float offsets)
#define OFF_A0   0          // [64rt][10f][2pl][64lane][16B bf16]  = 327680 floats
#define OFF_A1   327680     // [64rt][16f][2pl][64lane][16B bf16]  = 524288 floats
#define OFF_BP0  851968     // [1024] permuted fused bias layer0
#define OFF_BP1  852992     // [1024]
#define OFF_HEX  854016     // [2buf][16grp][16wgsrc][2layer][4uq][16b] u64 = 65536 u64 = 131072 floats
#define OFF_CNT  985088     // flags: 16 grp x 16 wg, 128B spacing = 8192 floats
#define WS_FLOATS (OFF_CNT + 8192)
// R5/R6 BUG (fixed): OFF_CNT was 919552 = OFF_HEX + 65536, i.e. hex sized in
// floats instead of u64 words -> flags lived inside hex buf1 (clobbered every
// odd tick) and buf1 of grps 2-15 sat in unzeroed poison past WS_FLOATS.

typedef __attribute__((ext_vector_type(8))) short  short8;
typedef __attribute__((ext_vector_type(4))) float  f32x4;
typedef __attribute__((ext_vector_type(8))) __bf16 bf16x8;
typedef unsigned long long u64;

__device__ __forceinline__ f32x4 mfma16(short8 a, short8 b, f32x4 c) {
  return __builtin_amdgcn_mfma_f32_16x16x32_bf16(
      __builtin_bit_cast(bf16x8, a), __builtin_bit_cast(bf16x8, b), c, 0, 0, 0);
}
__device__ __forceinline__ unsigned short f2bf(float f) {
  union { float f; unsigned u; } v{f};
  unsigned r = v.u + 0x7fffu + ((v.u >> 16) & 1u);   // RNE
  return (unsigned short)(r >> 16);
}
__device__ __forceinline__ float bf2f(unsigned short b) {
  union { unsigned u; float f; } v{(unsigned)b << 16};
  return v.f;
}
__device__ __forceinline__ u64 ld8(const u64* p) {
  return __hip_atomic_load(p, __ATOMIC_RELAXED, __HIP_MEMORY_SCOPE_AGENT);
}
__device__ __forceinline__ void st8(u64* p, u64 v) {
  __hip_atomic_store(p, v, __ATOMIC_RELAXED, __HIP_MEMORY_SCOPE_AGENT);
}
#define LOG2E 1.4426950408889634f
__device__ __forceinline__ float sigm(float x) {
  return __builtin_amdgcn_rcpf(1.0f + __builtin_amdgcn_exp2f(-x * LOG2E));
}
__device__ __forceinline__ float tanh_f(float x) {
  return 1.0f - 2.0f * __builtin_amdgcn_rcpf(1.0f + __builtin_amdgcn_exp2f(x * (2.0f * LOG2E)));
}

// ---- one-time weight swizzle into MFMA fragment order, hi/lo bf16 split.
__global__ void setup_kernel(const float* __restrict__ Wih0, const float* __restrict__ Whh0,
                             const float* __restrict__ bih0, const float* __restrict__ bhh0,
                             const float* __restrict__ Wih1, const float* __restrict__ Whh1,
                             const float* __restrict__ bih1, const float* __restrict__ bhh1,
                             float* __restrict__ ws) {
  int i = blockIdx.x * 256 + threadIdx.x;
  unsigned short* u = (unsigned short*)ws;
  if (i < 327680) {        // layer0: K = 320 (64 x | 256 h0)
    int rt = i / 5120, r = i % 5120;
    int f = r >> 9, l = (r >> 3) & 63, j = r & 7;
    int p = rt * 16 + (l & 15);
    int orig = (p & 3) * 256 + (p >> 2);
    int k = f * 32 + ((l >> 4) << 3) + j;
    float w = (k < 64) ? Wih0[orig * 64 + k] : Whh0[orig * 256 + k - 64];
    unsigned short hi = f2bf(w);
    unsigned short lo = f2bf(w - bf2f(hi));
    int base = OFF_A0 * 2 + (((rt * 10 + f) * 2) * 64 + l) * 8 + j;
    u[base] = hi; u[base + 512] = lo;
    return;
  }
  i -= 327680;
  if (i < 524288) {        // layer1: K = 512 (256 h0 | 256 h1)
    int rt = i >> 13, r = i & 8191;
    int f = r >> 9, l = (r >> 3) & 63, j = r & 7;
    int p = rt * 16 + (l & 15);
    int orig = (p & 3) * 256 + (p >> 2);
    int k = f * 32 + ((l >> 4) << 3) + j;
    float w = (k < 256) ? Wih1[orig * 256 + k] : Whh1[orig * 256 + k - 256];
    unsigned short hi = f2bf(w);
    unsigned short lo = f2bf(w - bf2f(hi));
    int base = OFF_A1 * 2 + (((rt * 16 + f) * 2) * 64 + l) * 8 + j;
    u[base] = hi; u[base + 512] = lo;
    return;
  }
  i -= 524288;
  if (i < 2048) {
    int layer = i >> 10, p = i & 1023;
    int orig = (p & 3) * 256 + (p >> 2);
    ws[OFF_BP0 + i] = layer ? (bih1[orig] + bhh1[orig]) : (bih0[orig] + bhh0[orig]);
  }
}

// hex word index: [buf][grp][wgsrc][layer][uq][b]
__device__ __forceinline__ int widx(int buf, int grp, int wgsrc, int layer, int uq, int b) {
  return ((((buf * 16 + grp) * 16 + wgsrc) * 2 + layer) * 4 + uq) * 16 + b;
}

// ---- persistent MFMA LSTM. 256 WGs x 512 thr; 16 groups x 16 WGs.
// waves 0-3: layer0 (step T); waves 4-7: layer1 (step T-1).
// Exports: inline in compute waves (shfl-pack, lanes 0-15 st8), then EACH
// wave drains its own stores (s_waitcnt vmcnt(0)) BEFORE bar2 -- so w2's
// release flag after bar2 publishes a fully-visible tick.
__global__ __launch_bounds__(512, 2) void lstm_mfma(
    const float* __restrict__ x, const float* __restrict__ targets,
    const float* __restrict__ fcW, const float* __restrict__ fcb,
    float* __restrict__ ws, float* __restrict__ out) {
  __shared__ __align__(16) short Bx[2][64][8];        // x frags
  __shared__ __align__(16) short Bh0[8][64][8];       // h0 frags
  __shared__ __align__(16) short Bh1[8][64][8];       // h1 frags (FC reads too)
  __shared__ float fcw_s[64 * 257];

  const int t = threadIdx.x;
  const int blk = blockIdx.x;
  const int xcd = blk & 7, slot = blk >> 3;
  const int grp = xcd * 2 + (slot >> 4);   // 0..15
  const int wg  = slot & 15;               // 0..15

  const int w = t >> 6, l = t & 63, wl = w & 3;
  const bool isL0 = (w < 4);
  const int rt = wg * 4 + wl;

  u64* hexw = (u64*)(ws + OFF_HEX);
  unsigned* flags = (unsigned*)(ws + OFF_CNT) + grp * 512;   // [wg*32]

  for (int idx = t; idx < 64 * 256; idx += 512)
    fcw_s[(idx >> 8) * 257 + (idx & 255)] = fcW[idx];

  // ---- register-resident A fragments
  short8 Ah[16], Al[16];
  if (isL0) {
    const float* Ab = ws + OFF_A0 + rt * 5120;
#pragma unroll
    for (int f = 0; f < 10; ++f) {
      Ah[f] = *(const short8*)(Ab + ((f * 2 + 0) * 64 + l) * 4);
      Al[f] = *(const short8*)(Ab + ((f * 2 + 1) * 64 + l) * 4);
    }
  } else {
    const float* Ab = ws + OFF_A1 + rt * 8192;
#pragma unroll
    for (int f = 0; f < 16; ++f) {
      Ah[f] = *(const short8*)(Ab + ((f * 2 + 0) * 64 + l) * 4);
      Al[f] = *(const short8*)(Ab + ((f * 2 + 1) * 64 + l) * 4);
    }
  }
  const f32x4 bias = *(const f32x4*)(ws + (isL0 ? OFF_BP0 : OFF_BP1) + rt * 16 + ((l >> 4) << 2));
  const float fcb_r = fcb[4 * wg + (l & 3)];
  float cst = 0.0f;

  const int col = l & 15;
  const int k0 = (w << 5) + ((l >> 4) << 3);
  const int wgsrc = k0 >> 4, uq0 = (k0 & 15) >> 2;   // uq0 in {0,2}

  float4 xr0, xr1;
  auto load_x = [&](int s) {     // issue global loads for step s into regs
    if (w < 2 && s < TSTEPS) {
      const float* src;
      if (s <= 512) {
        int ss = (s < 512) ? s : 511;
        src = x + ((size_t)(grp * 16 + col) * 512 + ss) * 64 + k0;
      } else {
        src = targets + ((size_t)(grp * 16 + col) * 128 + (s - 513)) * 64 + k0;
      }
      xr0 = *(const float4*)src;
      xr1 = *(const float4*)(src + 4);
    }
  };
  auto put_x = [&]() {           // regs -> Bx[w]
    if (w < 2) {
      short8 v;
      v[0] = (short)f2bf(xr0.x); v[1] = (short)f2bf(xr0.y);
      v[2] = (short)f2bf(xr0.z); v[3] = (short)f2bf(xr0.w);
      v[4] = (short)f2bf(xr1.x); v[5] = (short)f2bf(xr1.y);
      v[6] = (short)f2bf(xr1.z); v[7] = (short)f2bf(xr1.w);
      *(short8*)Bx[w][l] = v;
    }
  };

  load_x(0);

  for (int T = 0; T <= TSTEPS + 1; ++T) {
    const int rp = (T + 1) & 1, wp = T & 1;

    // ---- stage h0(T-1), h1(T-2) frags: private-block layout, lane-identity
    {
      const u64* b0 = hexw + widx(rp, grp, wgsrc, 0, uq0, col);
      u64 a0 = ld8(b0);
      u64 a1 = ld8(b0 + 16);        // uq0+1
      u64 a2 = ld8(b0 + 64);        // layer1, uq0
      u64 a3 = ld8(b0 + 80);        // layer1, uq0+1
      union { u64 q[2]; short8 v; } U;
      U.q[0] = a0; U.q[1] = a1; *(short8*)Bh0[w][l] = U.v;
      U.q[0] = a2; U.q[1] = a3; *(short8*)Bh1[w][l] = U.v;
    }
    if (T < TSTEPS) put_x();
    __syncthreads();                                   // bar1

    // ---- gate MFMA (hi/lo planes, 4 chains) + pointwise + inline export
    {
      const bool act = isL0 ? (T < TSTEPS) : (T >= 1 && T <= TSTEPS);
      if (act) {
        f32x4 aH0 = {0.f,0.f,0.f,0.f}, aH1 = {0.f,0.f,0.f,0.f};
        f32x4 aL0 = {0.f,0.f,0.f,0.f}, aL1 = {0.f,0.f,0.f,0.f};
        if (isL0) {
          {
            short8 b0 = *(const short8*)Bx[0][l];
            aH0 = mfma16(Ah[0], b0, aH0); aL0 = mfma16(Al[0], b0, aL0);
            short8 b1 = *(const short8*)Bx[1][l];
            aH1 = mfma16(Ah[1], b1, aH1); aL1 = mfma16(Al[1], b1, aL1);
          }
#pragma unroll
          for (int f = 2; f < 10; ++f) {
            short8 b = *(const short8*)Bh0[f - 2][l];
            if (f & 1) { aH1 = mfma16(Ah[f], b, aH1); aL1 = mfma16(Al[f], b, aL1); }
            else       { aH0 = mfma16(Ah[f], b, aH0); aL0 = mfma16(Al[f], b, aL0); }
          }
        } else {
#pragma unroll
          for (int f = 0; f < 8; ++f) {
            short8 b = *(const short8*)Bh0[f][l];
            if (f & 1) { aH1 = mfma16(Ah[f], b, aH1); aL1 = mfma16(Al[f], b, aL1); }
            else       { aH0 = mfma16(Ah[f], b, aH0); aL0 = mfma16(Al[f], b, aL0); }
          }
#pragma unroll
          for (int f = 8; f < 16; ++f) {
            short8 b = *(const short8*)Bh1[f - 8][l];
            if (f & 1) { aH1 = mfma16(Ah[f], b, aH1); aL1 = mfma16(Al[f], b, aL1); }
            else       { aH0 = mfma16(Ah[f], b, aH0); aL0 = mfma16(Al[f], b, aL0); }
          }
        }
        f32x4 s = aH0 + aH1 + aL0 + aL1 + bias;
        cst = sigm(s.y) * cst + sigm(s.x) * tanh_f(s.z);
        float hh = sigm(s.w) * tanh_f(cst);
        // inline export: pack 4 units (this wave's slice) for batch l&15
        unsigned bh = f2bf(hh);
        unsigned v0 = __shfl((int)bh, (l & 15));
        unsigned v1 = __shfl((int)bh, 16 + (l & 15));
        unsigned v2 = __shfl((int)bh, 32 + (l & 15));
        unsigned v3 = __shfl((int)bh, 48 + (l & 15));
        if (l < 16) {
          u64 q = ((u64)(v0 | (v1 << 16))) | (((u64)(v2 | (v3 << 16))) << 32);
          st8(hexw + widx(wp, grp, wg, isL0 ? 0 : 1, wl, l), q);
        }
        // drain THIS wave's exports before bar2 so w2's release flag
        // (after bar2) publishes a fully-visible tick.
        asm volatile("s_waitcnt vmcnt(0)" ::: "memory");
      }
    }
    __syncthreads();                                   // bar2

    // ---- end-phase (per-wave roles), then bar3 = tick boundary
    if (w == 2 && T <= TSTEPS && l == 0)
      __hip_atomic_store(&flags[wg * 32], (unsigned)(T + 1),
                         __ATOMIC_RELEASE, __HIP_MEMORY_SCOPE_AGENT);
    if (w < 2 && (T + 1) < TSTEPS) load_x(T + 1);   // prefetch next x into regs
    if (w == 3 && T >= 514) {         // FC projection (reads Bh1 = h1(T-2))
      int d = T - 514;
      int code = 4 * wg + (l & 3), b = l >> 2;
      float acc = fcb_r;
#pragma unroll 4
      for (int k8 = 0; k8 < 32; ++k8) {
        short8 hv = *(const short8*)Bh1[k8 >> 2][(k8 & 3) * 16 + b];
#pragma unroll
        for (int j = 0; j < 8; ++j)
          acc = fmaf(fcw_s[code * 257 + k8 * 8 + j], bf2f((unsigned short)hv[j]), acc);
      }
      __builtin_nontemporal_store(acc, &out[(size_t)(grp * 16 + b) * 8192 + d * 64 + code]);
    }
    if (w == 7 && T <= TSTEPS) {      // poll the group's 16 WG flags
      const unsigned tgt = (unsigned)(T + 1);
      bool ok;
      do {
        unsigned v = (l < 16) ? __hip_atomic_load(&flags[l * 32], __ATOMIC_RELAXED,
                                                  __HIP_MEMORY_SCOPE_AGENT)
                              : tgt;
        ok = __all(v >= tgt);
        if (!ok) __builtin_amdgcn_s_sleep(1);
      } while (!ok);
    }
    __syncthreads();                                   // bar3 (tick boundary)
  }
}

extern "C" void kernel_launch(void* const* d_in, const int* in_sizes, int n_in,
                              void* d_out, int out_size, void* d_ws, size_t ws_size,
                              hipStream_t stream) {
  const float* x       = (const float*)d_in[0];
  const float* targets = (const float*)d_in[1];
  const float* Wih0    = (const float*)d_in[2];
  const float* Whh0    = (const float*)d_in[3];
  const float* bih0    = (const float*)d_in[4];
  const float* bhh0    = (const float*)d_in[5];
  const float* Wih1    = (const float*)d_in[6];
  const float* Whh1    = (const float*)d_in[7];
  const float* bih1    = (const float*)d_in[8];
  const float* bhh1    = (const float*)d_in[9];
  const float* fcW     = (const float*)d_in[10];
  const float* fcb     = (const float*)d_in[11];
  float* ws = (float*)d_ws;
  float* o  = (float*)d_out;

  // zero h-exchange + flags every call (deterministic)
  hipMemsetAsync((char*)d_ws + (size_t)OFF_HEX * 4, 0,
                 (size_t)(WS_FLOATS - OFF_HEX) * 4, stream);
  setup_kernel<<<3336, 256, 0, stream>>>(Wih0, Whh0, bih0, bhh0,
                                         Wih1, Whh1, bih1, bhh1, ws);
  lstm_mfma<<<256, 512, 0, stream>>>(x, targets, fcW, fcb, ws, o);
}

// Round 8
// 1588.542 us; speedup vs baseline: 4.5827x; 1.9975x over previous
//
#include <hip/hip_runtime.h>
#include <math.h>

#define BATCH  256
#define CODE   64
#define HID    256
#define TSTEPS 640     // 512 encoder + 128 decoder steps
#define NGRP   16

// ---- workspace layout (float offsets)
#define OFF_A0   0          // [64rt][10f][2pl][64lane][16B bf16]  = 327680 floats
#define OFF_A1   327680     // [64rt][16f][2pl][64lane][16B bf16]  = 524288 floats
#define OFF_BP0  851968     // [1024] permuted fused bias layer0
#define OFF_BP1  852992     // [1024]
#define OFF_HEX  854016     // [2buf][16grp][16wgsrc][2layer][4uq][16b] x 16B = 2MB = 524288 floats
#define WS_FLOATS (OFF_HEX + 524288)

typedef __attribute__((ext_vector_type(8))) short  short8;
typedef __attribute__((ext_vector_type(4))) float  f32x4;
typedef __attribute__((ext_vector_type(4))) unsigned int u32x4;
typedef __attribute__((ext_vector_type(8))) __bf16 bf16x8;
typedef unsigned long long u64;

__device__ __forceinline__ f32x4 mfma16(short8 a, short8 b, f32x4 c) {
  return __builtin_amdgcn_mfma_f32_16x16x32_bf16(
      __builtin_bit_cast(bf16x8, a), __builtin_bit_cast(bf16x8, b), c, 0, 0, 0);
}
__device__ __forceinline__ unsigned short f2bf(float f) {
  union { float f; unsigned u; } v{f};
  unsigned r = v.u + 0x7fffu + ((v.u >> 16) & 1u);   // RNE
  return (unsigned short)(r >> 16);
}
__device__ __forceinline__ float bf2f(unsigned short b) {
  union { unsigned u; float f; } v{(unsigned)b << 16};
  return v.f;
}
#define LOG2E 1.4426950408889634f
__device__ __forceinline__ float sigm(float x) {
  return __builtin_amdgcn_rcpf(1.0f + __builtin_amdgcn_exp2f(-x * LOG2E));
}
__device__ __forceinline__ float tanh_f(float x) {
  return 1.0f - 2.0f * __builtin_amdgcn_rcpf(1.0f + __builtin_amdgcn_exp2f(x * (2.0f * LOG2E)));
}

// ---- one-time weight swizzle into MFMA fragment order, hi/lo bf16 split.
__global__ void setup_kernel(const float* __restrict__ Wih0, const float* __restrict__ Whh0,
                             const float* __restrict__ bih0, const float* __restrict__ bhh0,
                             const float* __restrict__ Wih1, const float* __restrict__ Whh1,
                             const float* __restrict__ bih1, const float* __restrict__ bhh1,
                             float* __restrict__ ws) {
  int i = blockIdx.x * 256 + threadIdx.x;
  unsigned short* u = (unsigned short*)ws;
  if (i < 327680) {        // layer0: K = 320 (64 x | 256 h0)
    int rt = i / 5120, r = i % 5120;
    int f = r >> 9, l = (r >> 3) & 63, j = r & 7;
    int p = rt * 16 + (l & 15);
    int orig = (p & 3) * 256 + (p >> 2);
    int k = f * 32 + ((l >> 4) << 3) + j;
    float w = (k < 64) ? Wih0[orig * 64 + k] : Whh0[orig * 256 + k - 64];
    unsigned short hi = f2bf(w);
    unsigned short lo = f2bf(w - bf2f(hi));
    int base = OFF_A0 * 2 + (((rt * 10 + f) * 2) * 64 + l) * 8 + j;
    u[base] = hi; u[base + 512] = lo;
    return;
  }
  i -= 327680;
  if (i < 524288) {        // layer1: K = 512 (256 h0 | 256 h1)
    int rt = i >> 13, r = i & 8191;
    int f = r >> 9, l = (r >> 3) & 63, j = r & 7;
    int p = rt * 16 + (l & 15);
    int orig = (p & 3) * 256 + (p >> 2);
    int k = f * 32 + ((l >> 4) << 3) + j;
    float w = (k < 256) ? Wih1[orig * 256 + k] : Whh1[orig * 256 + k - 256];
    unsigned short hi = f2bf(w);
    unsigned short lo = f2bf(w - bf2f(hi));
    int base = OFF_A1 * 2 + (((rt * 16 + f) * 2) * 64 + l) * 8 + j;
    u[base] = hi; u[base + 512] = lo;
    return;
  }
  i -= 524288;
  if (i < 2048) {
    int layer = i >> 10, p = i & 1023;
    int orig = (p & 3) * 256 + (p >> 2);
    ws[OFF_BP0 + i] = layer ? (bih1[orig] + bhh1[orig]) : (bih0[orig] + bhh0[orig]);
  }
}

// quantum byte offset: [buf][grp][wgsrc][layer][uq][b] x 16B
// quantum = {tagA, units[4uq..4uq+1] bf16x2, units[4uq+2..4uq+3], tagB}
__device__ __forceinline__ size_t qoff(int buf, int grp, int wgsrc, int layer, int uq, int b) {
  return (size_t)(((((buf * 16 + grp) * 16 + wgsrc) * 2 + layer) * 4 + uq) * 16 + b) * 16u;
}

// ---- persistent MFMA LSTM, tagged-quantum sync (no flags, no drain, no poll wave).
// 256 WGs x 512 thr; 16 groups x 16 WGs. waves 0-3: layer0 (step T);
// waves 4-7: layer1 (step T-1). Every wave exports its 4-unit x 16-batch slice
// as tagged 16B quanta each tick, then polls the 4 quanta it needs next tick.
__global__ __launch_bounds__(512, 2) void lstm_mfma(
    const float* __restrict__ x, const float* __restrict__ targets,
    const float* __restrict__ fcW, const float* __restrict__ fcb,
    float* __restrict__ ws, float* __restrict__ out) {
  __shared__ __align__(16) short Bx[2][64][8];        // x frags
  __shared__ __align__(16) short Bh0[8][64][8];       // h0 frags
  __shared__ __align__(16) short Bh1[8][64][8];       // h1 frags (FC reads too)
  __shared__ float fcw_s[64 * 257];

  const int t = threadIdx.x;
  const int blk = blockIdx.x;
  const int xcd = blk & 7, slot = blk >> 3;
  const int grp = xcd * 2 + (slot >> 4);   // 0..15
  const int wg  = slot & 15;               // 0..15

  const int w = t >> 6, l = t & 63, wl = w & 3;
  const bool isL0 = (w < 4);
  const int rt = wg * 4 + wl;

  char* hexb = (char*)(ws + OFF_HEX);

  for (int idx = t; idx < 64 * 256; idx += 512)
    fcw_s[(idx >> 8) * 257 + (idx & 255)] = fcW[idx];

  // ---- register-resident A fragments
  short8 Ah[16], Al[16];
  if (isL0) {
    const float* Ab = ws + OFF_A0 + rt * 5120;
#pragma unroll
    for (int f = 0; f < 10; ++f) {
      Ah[f] = *(const short8*)(Ab + ((f * 2 + 0) * 64 + l) * 4);
      Al[f] = *(const short8*)(Ab + ((f * 2 + 1) * 64 + l) * 4);
    }
  } else {
    const float* Ab = ws + OFF_A1 + rt * 8192;
#pragma unroll
    for (int f = 0; f < 16; ++f) {
      Ah[f] = *(const short8*)(Ab + ((f * 2 + 0) * 64 + l) * 4);
      Al[f] = *(const short8*)(Ab + ((f * 2 + 1) * 64 + l) * 4);
    }
  }
  const f32x4 bias = *(const f32x4*)(ws + (isL0 ? OFF_BP0 : OFF_BP1) + rt * 16 + ((l >> 4) << 2));
  const float fcb_r = fcb[4 * wg + (l & 3)];
  float cst = 0.0f;

  const int col = l & 15;
  const int k0 = (w << 5) + ((l >> 4) << 3);
  const int wgsrc = k0 >> 4, uq0 = (k0 & 15) >> 2;   // uq0 in {0,2}

  float4 xr0, xr1;
  auto load_x = [&](int s) {
    if (w < 2 && s < TSTEPS) {
      const float* src;
      if (s <= 512) {
        int ss = (s < 512) ? s : 511;
        src = x + ((size_t)(grp * 16 + col) * 512 + ss) * 64 + k0;
      } else {
        src = targets + ((size_t)(grp * 16 + col) * 128 + (s - 513)) * 64 + k0;
      }
      xr0 = *(const float4*)src;
      xr1 = *(const float4*)(src + 4);
    }
  };
  auto put_x = [&]() {
    if (w < 2) {
      short8 v;
      v[0] = (short)f2bf(xr0.x); v[1] = (short)f2bf(xr0.y);
      v[2] = (short)f2bf(xr0.z); v[3] = (short)f2bf(xr0.w);
      v[4] = (short)f2bf(xr1.x); v[5] = (short)f2bf(xr1.y);
      v[6] = (short)f2bf(xr1.z); v[7] = (short)f2bf(xr1.w);
      *(short8*)Bx[w][l] = v;
    }
  };

  // ---- prologue: zero h frags, stage x(0)
  *(u32x4*)&Bh0[w][l][0] = u32x4{0, 0, 0, 0};
  *(u32x4*)&Bh1[w][l][0] = u32x4{0, 0, 0, 0};
  load_x(0); put_x();
  __syncthreads();

  u32x4 q00, q01, q10, q11;   // staged tagged quanta (regs across bar2)

  for (int T = 0; T <= TSTEPS + 1; ++T) {
    // ---- compute phase
    float hh = 0.0f;
    const bool act = isL0 ? (T < TSTEPS) : (T >= 1 && T <= TSTEPS);
    if (act) {
      f32x4 aH0 = {0.f,0.f,0.f,0.f}, aH1 = {0.f,0.f,0.f,0.f};
      f32x4 aL0 = {0.f,0.f,0.f,0.f}, aL1 = {0.f,0.f,0.f,0.f};
      if (isL0) {
        {
          short8 b0 = *(const short8*)Bx[0][l];
          aH0 = mfma16(Ah[0], b0, aH0); aL0 = mfma16(Al[0], b0, aL0);
          short8 b1 = *(const short8*)Bx[1][l];
          aH1 = mfma16(Ah[1], b1, aH1); aL1 = mfma16(Al[1], b1, aL1);
        }
#pragma unroll
        for (int f = 2; f < 10; ++f) {
          short8 b = *(const short8*)Bh0[f - 2][l];
          if (f & 1) { aH1 = mfma16(Ah[f], b, aH1); aL1 = mfma16(Al[f], b, aL1); }
          else       { aH0 = mfma16(Ah[f], b, aH0); aL0 = mfma16(Al[f], b, aL0); }
        }
      } else {
#pragma unroll
        for (int f = 0; f < 8; ++f) {
          short8 b = *(const short8*)Bh0[f][l];
          if (f & 1) { aH1 = mfma16(Ah[f], b, aH1); aL1 = mfma16(Al[f], b, aL1); }
          else       { aH0 = mfma16(Ah[f], b, aH0); aL0 = mfma16(Al[f], b, aL0); }
        }
#pragma unroll
        for (int f = 8; f < 16; ++f) {
          short8 b = *(const short8*)Bh1[f - 8][l];
          if (f & 1) { aH1 = mfma16(Ah[f], b, aH1); aL1 = mfma16(Al[f], b, aL1); }
          else       { aH0 = mfma16(Ah[f], b, aH0); aL0 = mfma16(Al[f], b, aL0); }
        }
      }
      f32x4 s = aH0 + aH1 + aL0 + aL1 + bias;
      cst = sigm(s.y) * cst + sigm(s.x) * tanh_f(s.z);
      hh = sigm(s.w) * tanh_f(cst);
    }

    const unsigned tag = (unsigned)(T + 1);

    // ---- export: shfl-pack 4 units x batch, single tagged 16B store (no drain)
    if (T <= TSTEPS) {
      unsigned bh = f2bf(hh);
      unsigned v0 = __shfl((int)bh, (l & 15));
      unsigned v1 = __shfl((int)bh, 16 + (l & 15));
      unsigned v2 = __shfl((int)bh, 32 + (l & 15));
      unsigned v3 = __shfl((int)bh, 48 + (l & 15));
      if (l < 16) {
        u32x4 ex = {tag, v0 | (v1 << 16), v2 | (v3 << 16), tag};
        char* pe = hexb + qoff(T & 1, grp, wg, isL0 ? 0 : 1, wl, l);
        asm volatile("global_store_dwordx4 %0, %1, off sc0 sc1"
                     :: "v"(pe), "v"(ex) : "memory");
      }
    }

    if (w < 2 && (T + 1) < TSTEPS) load_x(T + 1);   // x prefetch into regs

    if (w == 3 && T >= 514) {        // FC projection (reads Bh1 = h1(T-2))
      int d = T - 514;
      int code = 4 * wg + (l & 3), b = l >> 2;
      float acc = fcb_r;
#pragma unroll 4
      for (int k8 = 0; k8 < 32; ++k8) {
        short8 hv = *(const short8*)Bh1[k8 >> 2][(k8 & 3) * 16 + b];
#pragma unroll
        for (int j = 0; j < 8; ++j)
          acc = fmaf(fcw_s[code * 257 + k8 * 8 + j], bf2f((unsigned short)hv[j]), acc);
      }
      __builtin_nontemporal_store(acc, &out[(size_t)(grp * 16 + b) * 8192 + d * 64 + code]);
    }

    // ---- poll: re-load own 4 quanta until both tags match (self-throttled by RT)
    if (T <= TSTEPS) {
      char* pb = hexb + qoff(T & 1, grp, wgsrc, 0, uq0, col);
      while (true) {
        asm volatile(
            "global_load_dwordx4 %0, %4, off sc0 sc1\n\t"
            "global_load_dwordx4 %1, %4, off offset:256 sc0 sc1\n\t"
            "global_load_dwordx4 %2, %4, off offset:1024 sc0 sc1\n\t"
            "global_load_dwordx4 %3, %4, off offset:1280 sc0 sc1\n\t"
            "s_waitcnt vmcnt(0)"
            : "=v"(q00), "=v"(q01), "=v"(q10), "=v"(q11)
            : "v"(pb) : "memory");
        bool ok = (q00.x == tag) & (q00.w == tag) & (q01.x == tag) & (q01.w == tag) &
                  (q10.x == tag) & (q10.w == tag) & (q11.x == tag) & (q11.w == tag);
        if (__all(ok)) break;
      }
    }
    __syncthreads();                                   // bar2: compute-reads done

    // ---- LDS write phase: staged quanta -> frags for tick T+1
    if (T <= TSTEPS) {
      *(u32x4*)&Bh0[w][l][0] = u32x4{q00.y, q00.z, q01.y, q01.z};
      *(u32x4*)&Bh1[w][l][0] = u32x4{q10.y, q10.z, q11.y, q11.z};
      if ((T + 1) < TSTEPS) put_x();
    }
    __syncthreads();                                   // bar1: frags ready
  }
}

extern "C" void kernel_launch(void* const* d_in, const int* in_sizes, int n_in,
                              void* d_out, int out_size, void* d_ws, size_t ws_size,
                              hipStream_t stream) {
  const float* x       = (const float*)d_in[0];
  const float* targets = (const float*)d_in[1];
  const float* Wih0    = (const float*)d_in[2];
  const float* Whh0    = (const float*)d_in[3];
  const float* bih0    = (const float*)d_in[4];
  const float* bhh0    = (const float*)d_in[5];
  const float* Wih1    = (const float*)d_in[6];
  const float* Whh1    = (const float*)d_in[7];
  const float* bih1    = (const float*)d_in[8];
  const float* bhh1    = (const float*)d_in[9];
  const float* fcW     = (const float*)d_in[10];
  const float* fcb     = (const float*)d_in[11];
  float* ws = (float*)d_ws;
  float* o  = (float*)d_out;

  // zero tagged h-exchange every call (tag 0 == "initial zeros", deterministic)
  hipMemsetAsync((char*)d_ws + (size_t)OFF_HEX * 4, 0, (size_t)524288 * 4, stream);
  setup_kernel<<<3336, 256, 0, stream>>>(Wih0, Whh0, bih0, bhh0,
                                         Wih1, Whh1, bih1, bhh1, ws);
  lstm_mfma<<<256, 512, 0, stream>>>(x, targets, fcW, fcb, ws, o);
}